// Round 10
// baseline (251.696 us; speedup 1.0000x reference)
//
#include <hip/hip_runtime.h>
#include <stdint.h>

// VectorQuantizer — argmin-exact via MFMA filter + bit-exact verify.
//
// r0-r9 boxed in the VALU-exact approach: 67M exact 81-op chains = 71us
// issue floor, plus un-hideable row fetch (s_load drains, LDS pipe
// occupancy, vector-global TA tax) -> ~137us plateau. But the OUTPUT only
// needs numpy's argmin: z_q rows are bitwise codebook copies and indices
// are ints. So: (1) bf16 MFMA computes d'[n,k] ~= cnorm_k - 2 z.c for all
// pairs (cnorm in acc-init; z scaled by -2 exactly pre-split); (2) per
// point: min d' + candidates within DELTA; (3) recompute the PROVEN
// bit-exact numpy chain only for ~2-4 candidates/pt, strict < with k
// tie-break -> argmin identical to reference.
//
// Error bound: |d' - (d - sz)| <= 2||z||*||c - bf16(c)|| + 2||resid|| +
// accum ~= 8e-4 worst (||z||<=11.5 @6sigma); DELTA=0.01 -> 12x margin.
// Robustness: MFMA K-slot permutation CANCELS (A,B frags built with the
// same slot->channel formula); load-bearing layout facts: m/n = lane&15
// (A row / B col), C/D col=lane&15 row=(lane>>4)*4+reg [m89-verified].
//
// Structure: strip = 16 points; wave: 4 strips; block 256 thr (4 waves);
// 512 blocks. B-frags (codebook bf16, 64KB) prepped once into d_ws,
// read per-tile from global (L2-hot). acc[32] f32x4/lane = 4 pts x 32
// codes. Verify reads zz from per-wave LDS + cb row from global.
// Fallback (ws too small): proven r5 s_load kernel (137us).

#pragma clang fp contract(off)

#define KCODES 512
#define CDIM 64
#define HW 4096              // 64*64
#define ZQ_ELEMS 8388608     // 32*64*64*64
#define DELTA 0.01f

typedef float f32x4 __attribute__((ext_vector_type(4)));
typedef unsigned short us8 __attribute__((ext_vector_type(8)));

// round-to-nearest-even fp32 -> bf16 bits (no NaN/Inf in our data)
static __device__ __forceinline__ unsigned short bf16_rne(float f) {
    union { float f; unsigned u; } x; x.f = f;
    unsigned lsb = (x.u >> 16) & 1u;
    return (unsigned short)((x.u + 0x7FFFu + lsb) >> 16);
}

// D = A(16x32 bf16) * B(32x16 bf16) + C ; all operands in arch VGPRs
static __device__ __forceinline__ f32x4 mfma_bf16(us8 a, us8 b, f32x4 c) {
    f32x4 d;
    asm("v_mfma_f32_16x16x32_bf16 %0, %1, %2, %3"
        : "=v"(d) : "v"(a), "v"(b), "v"(c));
    return d;
}

// np.sum(row*row): pairwise_sum n=64 replica (products pre-rounded)
static __device__ __forceinline__ float cnorm_row(const float* __restrict__ row) {
    float r[8];
    #pragma unroll
    for (int j = 0; j < 8; ++j) r[j] = row[j] * row[j];
    #pragma unroll
    for (int i = 8; i < 64; i += 8) {
        #pragma unroll
        for (int j = 0; j < 8; ++j) r[j] = r[j] + row[i + j] * row[i + j];
    }
    return ((r[0] + r[1]) + (r[2] + r[3])) + ((r[4] + r[5]) + (r[6] + r[7]));
}

// One-shot: cnorm[512] (exact fp32) into ws[0..512)
__global__ void cnorm_kernel(const float* __restrict__ cb,
                             float* __restrict__ ws) {
    int k = (int)blockIdx.x * 256 + (int)threadIdx.x;
    if (k < KCODES) ws[k] = cnorm_row(cb + (size_t)k * CDIM);
}

// One-shot: codebook bf16 B-fragments into ws[512..): layout
// frag[((t*2+kh)*64 + lane)*8 + i] = bf16(cb[t*16+(lane&15)][kh*32+8*((lane>>4)&3)+i])
__global__ void cbfrag_kernel(const float* __restrict__ cb,
                              float* __restrict__ ws) {
    int idx = (int)blockIdx.x * 256 + (int)threadIdx.x;   // 0..32767
    unsigned short* fr = (unsigned short*)(ws + KCODES);
    int i  = idx & 7;
    int ln = (idx >> 3) & 63;
    int kh = (idx >> 9) & 1;
    int t  = idx >> 10;
    int code = t * 16 + (ln & 15);
    int ch   = kh * 32 + ((ln >> 4) & 3) * 8 + i;
    fr[idx] = bf16_rne(cb[(size_t)code * CDIM + ch]);
}

// ---------------- MFMA filter + exact-verify kernel ----------------
__global__ __launch_bounds__(256)
void vq_mfma(const float* __restrict__ z_e,
             const float* __restrict__ cb,
             const float* __restrict__ ws,    // [0,512): cnorm; [512,..): frags
             float* __restrict__ out)
{
    __shared__ float cnorm_s[KCODES];
    __shared__ __align__(16) float zz_s[4][16][68];  // per-wave strip z (pad 68)
    __shared__ float sz_s[4][16];

    const int tid  = (int)threadIdx.x;
    const int lane = tid & 63;
    const int wid  = tid >> 6;
    const int grp  = lane >> 4;     // 0..3
    const int col  = lane & 15;     // A-row (point) / B-col (code) id

    cnorm_s[tid]       = ws[tid];
    cnorm_s[tid + 256] = ws[tid + 256];
    __syncthreads();

    const us8* __restrict__ frag = (const us8*)(ws + KCODES);

    // per-lane cnorm for acc-init: this lane's code column is t*16+col
    float cnr[32];
    #pragma unroll
    for (int t = 0; t < 32; ++t) cnr[t] = cnorm_s[t * 16 + col];

    for (int s = 0; s < 4; ++s) {
        const int n0s = (int)blockIdx.x * 256 + wid * 64 + s * 16;
        const int b   = n0s / HW;
        const int hw0 = n0s % HW;
        const float* zbase = z_e + (size_t)b * CDIM * HW + hw0;

        // ---- load z: lane owns point p=col, channels {kh*32+8*grp+i} ----
        float zv[16];
        #pragma unroll
        for (int kh = 0; kh < 2; ++kh)
            #pragma unroll
            for (int i = 0; i < 8; ++i)
                zv[kh * 8 + i] = zbase[(size_t)(kh * 32 + grp * 8 + i) * HW + col];

        // stash strip z in LDS (bitwise) for the exact-verify chains
        #pragma unroll
        for (int kh = 0; kh < 2; ++kh)
            #pragma unroll
            for (int ih = 0; ih < 2; ++ih) {
                f32x4 t4 = { zv[kh*8 + ih*4 + 0], zv[kh*8 + ih*4 + 1],
                             zv[kh*8 + ih*4 + 2], zv[kh*8 + ih*4 + 3] };
                int c0 = kh * 32 + grp * 8 + ih * 4;      // 16B aligned
                *(f32x4*)&zz_s[wid][col][c0] = t4;
            }

        // A-frags: bf16(-2*z) (-2x exact in fp32 before rounding)
        us8 za0, za1;
        #pragma unroll
        for (int i = 0; i < 8; ++i) za0[i] = bf16_rne(-2.0f * zv[i]);
        #pragma unroll
        for (int i = 0; i < 8; ++i) za1[i] = bf16_rne(-2.0f * zv[8 + i]);

        // ---- exact sz (numpy pairwise), wave-parallel, point=col ----
        // lane computes chains j=2*grp, 2*grp+1; tree via commutative shfl adds
        float r0, r1;
        {
            float a0 = zz_s[wid][col][2 * grp];
            float b0 = zz_s[wid][col][2 * grp + 1];
            r0 = a0 * a0; r1 = b0 * b0;
            #pragma unroll
            for (int ii = 1; ii < 8; ++ii) {
                float av = zz_s[wid][col][ii * 8 + 2 * grp];
                float bv = zz_s[wid][col][ii * 8 + 2 * grp + 1];
                r0 = r0 + av * av; r1 = r1 + bv * bv;
            }
        }
        float tj = r0 + r1;                    // t_grp = r[2g]+r[2g+1]
        float u  = tj + __shfl_xor(tj, 16);    // (t0+t1) / (t2+t3)
        float szp = u + __shfl_xor(u, 32);     // ((t0+t1)+(t2+t3)) exact tree
        if (grp == 0) sz_s[wid][col] = szp;

        // ---- MFMA: acc[t][r] = d'[point grp*4+r][code t*16+col] ----
        f32x4 acc[32];
        #pragma unroll
        for (int t = 0; t < 32; ++t) {
            f32x4 ai = { cnr[t], cnr[t], cnr[t], cnr[t] };
            us8 bf0 = frag[(t * 2 + 0) * 64 + lane];
            us8 bf1 = frag[(t * 2 + 1) * 64 + lane];
            f32x4 m0 = mfma_bf16(za0, bf0, ai);
            acc[t] = mfma_bf16(za1, bf1, m0);
        }

        // ---- per-point min over 512 codes ----
        float mn[4];
        #pragma unroll
        for (int r = 0; r < 4; ++r) {
            float m = acc[0][r];
            #pragma unroll
            for (int t = 1; t < 32; ++t) m = fminf(m, acc[t][r]);
            m = fminf(m, __shfl_xor(m, 1));
            m = fminf(m, __shfl_xor(m, 2));
            m = fminf(m, __shfl_xor(m, 4));
            m = fminf(m, __shfl_xor(m, 8));
            mn[r] = m;
        }

        // ---- candidate masks (k = t*16+col per bit t) ----
        unsigned msk[4];
        #pragma unroll
        for (int r = 0; r < 4; ++r) {
            float th = mn[r] + DELTA;
            unsigned m = 0;
            #pragma unroll
            for (int t = 0; t < 32; ++t)
                m |= (acc[t][r] <= th) ? (1u << t) : 0u;
            msk[r] = m;
        }

        // ---- exact verify (proven numpy chain) over candidates ----
        float bd[4]; int bk[4];
        #pragma unroll
        for (int r = 0; r < 4; ++r) {
            bd[r] = 3.4e38f; bk[r] = 0x7fffffff;
            const int p = grp * 4 + r;
            unsigned m = msk[r];
            if (m) {
                const float szv = sz_s[wid][p];
                const float* zzp = &zz_s[wid][p][0];
                while (m) {
                    int t = __builtin_ctz(m); m &= m - 1;
                    int k = t * 16 + col;               // ascending within lane
                    const float* ck = cb + (size_t)k * CDIM;
                    float v[16];
                    #pragma unroll
                    for (int l2 = 0; l2 < 16; ++l2)
                        v[l2] = fmaf(zzp[l2], ck[l2],
                                 fmaf(zzp[16 + l2], ck[16 + l2],
                                   fmaf(zzp[32 + l2], ck[32 + l2],
                                     fmaf(zzp[48 + l2], ck[48 + l2], 0.f))));
                    float e[8];
                    #pragma unroll
                    for (int l2 = 0; l2 < 8; ++l2) e[l2] = v[l2] + v[8 + l2];
                    float f4[4];
                    #pragma unroll
                    for (int l2 = 0; l2 < 4; ++l2) f4[l2] = e[l2] + e[4 + l2];
                    float g0 = f4[0] + f4[2];
                    float g1 = f4[1] + f4[3];
                    float dot = g0 + g1;
                    float A = szv + cnorm_s[k];          // fl(sz + sc_k)
                    float d = fmaf(dot, -2.f, A);        // fl(A - 2*dot)
                    if (d < bd[r]) { bd[r] = d; bk[r] = k; }  // strict <
                }
            }
            // cross-lane combine (16-group), tie-break smaller k
            #pragma unroll
            for (int mlog = 0; mlog < 4; ++mlog) {
                float od = __shfl_xor(bd[r], 1 << mlog);
                int   ok = __shfl_xor(bk[r], 1 << mlog);
                if (od < bd[r] || (od == bd[r] && ok < bk[r])) {
                    bd[r] = od; bk[r] = ok;
                }
            }
        }

        // ---- distribute winner of point p=col to all lanes ----
        int srcl = (col >> 2) << 4;       // a lane of the group owning point col
        int b0v = __shfl(bk[0], srcl);
        int b1v = __shfl(bk[1], srcl);
        int b2v = __shfl(bk[2], srcl);
        int b3v = __shfl(bk[3], srcl);
        int rsel = col & 3;
        int bkp = rsel == 0 ? b0v : rsel == 1 ? b1v : rsel == 2 ? b2v : b3v;

        // indices (as float32, second output region)
        if (lane < 16) out[ZQ_ELEMS + n0s + lane] = (float)bkp;

        // z_q: bitwise codebook rows; lane writes point col, channels grp+4j
        const float* rowp = cb + (size_t)bkp * CDIM;
        float* op = out + (size_t)b * CDIM * HW + hw0 + col;
        #pragma unroll
        for (int j = 0; j < 16; ++j) {
            int c = grp + 4 * j;
            op[(size_t)c * HW] = rowp[c];
        }
    }
}

// ---------------- s_load fallback (proven r5 kernel, 137us) ----------------
__global__ __launch_bounds__(256)
void vq_sload(const float* __restrict__ z_e,
              const float* __restrict__ cb,
              const float* __restrict__ cnorm_g,
              float* __restrict__ out)
{
    __shared__ float cnorm[KCODES];
    __shared__ float dcand[4 * 64];
    __shared__ int   kcand[4 * 64];

    for (int k = (int)threadIdx.x; k < KCODES; k += 256)
        cnorm[k] = cnorm_g ? cnorm_g[k] : cnorm_row(cb + (size_t)k * CDIM);

    const int lane = (int)threadIdx.x & 63;
    const int g = __builtin_amdgcn_readfirstlane((int)threadIdx.x >> 6);
    const int n0 = (int)blockIdx.x * 64;
    const int b = n0 / HW;
    const int hw0 = n0 % HW;
    const float* zp = z_e + (size_t)b * CDIM * HW + hw0 + lane;

    float zz[CDIM];
    #pragma unroll
    for (int m = 0; m < CDIM; ++m) zz[m] = zp[(size_t)m * HW];

    float sz;
    {
        float r[8];
        #pragma unroll
        for (int j = 0; j < 8; ++j) r[j] = zz[j] * zz[j];
        #pragma unroll
        for (int i = 8; i < 64; i += 8) {
            #pragma unroll
            for (int j = 0; j < 8; ++j) r[j] = r[j] + zz[i + j] * zz[i + j];
        }
        sz = ((r[0] + r[1]) + (r[2] + r[3])) + ((r[4] + r[5]) + (r[6] + r[7]));
    }

    __syncthreads();

    float best = 3.4e38f;
    int bk = 0;
    const int k0 = g * 128;

    for (int i = 0; i < 128; ++i) {
        const int k = k0 + i;
        const float* ck = cb + (size_t)k * CDIM;
        float v[16];
        #pragma unroll
        for (int l = 0; l < 16; ++l)
            v[l] = fmaf(zz[l], ck[l],
                     fmaf(zz[16 + l], ck[16 + l],
                       fmaf(zz[32 + l], ck[32 + l],
                         fmaf(zz[48 + l], ck[48 + l], 0.f))));
        float e[8];
        #pragma unroll
        for (int l = 0; l < 8; ++l) e[l] = v[l] + v[8 + l];
        float f[4];
        #pragma unroll
        for (int l = 0; l < 4; ++l) f[l] = e[l] + e[4 + l];
        float dot = (f[0] + f[2]) + (f[1] + f[3]);
        float A = sz + cnorm[k];
        float d = fmaf(dot, -2.f, A);
        if (d < best) { best = d; bk = k; }
    }

    dcand[g * 64 + lane] = best;
    kcand[g * 64 + lane] = bk;
    __syncthreads();

    float bd = dcand[lane];
    int bi = kcand[lane];
    #pragma unroll
    for (int gg = 1; gg < 4; ++gg) {
        float d2 = dcand[gg * 64 + lane];
        int   k2 = kcand[gg * 64 + lane];
        if (d2 < bd) { bd = d2; bi = k2; }
    }

    if (g == 0) out[ZQ_ELEMS + n0 + lane] = (float)bi;

    const float* row = cb + (size_t)bi * CDIM;
    float* op = out + (size_t)b * CDIM * HW + hw0 + lane;
    #pragma unroll
    for (int c = 0; c < 16; ++c) {
        const int ch = g * 16 + c;
        op[(size_t)ch * HW] = row[ch];
    }
}

extern "C" void kernel_launch(void* const* d_in, const int* in_sizes, int n_in,
                              void* d_out, int out_size, void* d_ws, size_t ws_size,
                              hipStream_t stream) {
    const float* z_e = (const float*)d_in[0];
    const float* cb  = (const float*)d_in[1];
    float* out = (float*)d_out;

    const size_t ws_need = KCODES * 4 + 32768 * 2;   // cnorm + bf16 frags
    if (ws_size >= ws_need) {
        float* ws = (float*)d_ws;
        cnorm_kernel<<<dim3(2), dim3(256), 0, stream>>>(cb, ws);
        cbfrag_kernel<<<dim3(128), dim3(256), 0, stream>>>(cb, ws);
        vq_mfma<<<dim3(512), dim3(256), 0, stream>>>(z_e, cb, ws, out);
    } else {
        vq_sload<<<dim3(2048), dim3(256), 0, stream>>>(z_e, cb, nullptr, out);
    }
}